// Round 4
// baseline (427.428 us; speedup 1.0000x reference)
//
#include <hip/hip_runtime.h>

// Fused SLAYER 2-layer SNN forward, time-chunked bitmask version, 512-thread
// blocks. Grid 512 blocks x 8 waves = 16 waves/CU (was 8) to fix the
// occupancy-bound plateau seen in rocprof (Occupancy 19%, VALUBusy 52%).
//
// psp commutes with the per-timestep spatial conv -> conv BINARY spikes,
// apply psp after. Spikes are bitmasks; convs amortize LDS mask/weight reads
// over TC=10 timesteps. Work is contiguous-assigned so idle waves skip via
// execz: waves 0-5 layer-1 (324 px), waves 0-3 layer-2/output (256 px).
// Recurrence arithmetic identical to the passing R3 kernel (absmax 0).

#define TILE 16
#define R1S  22                 // x-mask region: TILE + 2*(2+1)
#define R1N  (R1S * R1S)        // 484
#define R2S  18                 // layer-1 spike region: TILE + 2*1
#define R2N  (R2S * R2S)        // 324
#define TC   10                 // timesteps per chunk (50 = 5 chunks)

__global__ __launch_bounds__(512, 4)
void snn_fused(const float* __restrict__ xin,
               const float* __restrict__ w1,
               const float* __restrict__ w2,
               float* __restrict__ out)
{
    __shared__ __align__(16) uint2    xm[4][R1N];   // input spike masks (all 50 t)
    __shared__ unsigned               s1m[4][R2N];  // layer-1 spike masks (per chunk)
    __shared__ __align__(16) float    wL1[400];     // [ic][dy][dx][oc]
    __shared__ __align__(16) float    wL2[144];     // [ic][dy][dx][oc]

    const int tid = threadIdx.x;
    const int n   = blockIdx.z;
    const int Y0  = blockIdx.y * TILE;
    const int X0  = blockIdx.x * TILE;

    // ---- stage weights, transposed to [ic][dy][dx][oc] ----
    if (tid < 400) {
        int i = tid;
        int oc = i & 3, r = i >> 2;
        int ic = r / 25, r2 = r - ic * 25;
        int dy = r2 / 5, dx = r2 - dy * 5;
        wL1[i] = w1[((oc * 4 + ic) * 5 + dy) * 5 + dx];
    }
    if (tid < 144) {
        int oc = tid & 3, r = tid >> 2;
        int ic = r / 9, r2 = r - ic * 9;
        int dy = r2 / 3, dx = r2 - dy * 3;
        wL2[tid] = w2[((oc * 4 + ic) * 3 + dy) * 3 + dx];
    }

    // ---- pack input spikes (50 floats) into 64-bit masks, once ----
    if (tid < R1N) {
        int hy = tid / R1S, hx = tid - hy * R1S;
        int gy = Y0 + hy - 3, gx = X0 + hx - 3;
        bool inimg = gy >= 0 && gy < 128 && gx >= 0 && gx < 128;
#pragma unroll
        for (int c = 0; c < 4; ++c) {
            unsigned m0 = 0, m1 = 0;
            if (inimg) {
                const float2* p = (const float2*)
                    (xin + ((size_t)(((n * 4 + c) * 128 + gy) * 128 + gx)) * 50);
#pragma unroll
                for (int j = 0; j < 25; ++j) {
                    float2 v = p[j];
                    unsigned b0 = (v.x != 0.f) ? 1u : 0u;
                    unsigned b1 = (v.y != 0.f) ? 1u : 0u;
                    int k = 2 * j;
                    if (k < 32) m0 |= (b0 << k) | (b1 << (k + 1));
                    else        m1 |= (b0 << (k - 32)) | (b1 << (k - 31));
                }
            }
            xm[c][tid] = make_uint2(m0, m1);
        }
    }

    // ---- layer-1 region slot (18x18 = 324 px on waves 0-5, contiguous) ----
    const bool cw = (tid < R2N);
    int cy = tid / R2S;
    int cx = tid - cy * R2S;
    {
        int gy = Y0 + cy - 1, gx = X0 + cx - 1;
        // cin computed below uses these
        (void)gy; (void)gx;
    }
    const bool cin = cw && (Y0 + cy - 1) >= 0 && (Y0 + cy - 1) < 128
                        && (X0 + cx - 1) >= 0 && (X0 + cx - 1) < 128;
    const int xbase = cy * R1S + cx;

    // ---- interior pixel (waves 0-3) ----
    const int iy = (tid >> 4) & 15, ix = tid & 15;
    const int ibase = iy * R2S + ix;

    // persistent recurrence states
    float s1a[4] = {}, s2a[4] = {}, s1b[4] = {}, s2b[4] = {};
    float s1c[4] = {}, s2c[4] = {}, s1d[4] = {}, s2d[4] = {};
    unsigned long long om[4] = {};

    const float R1  = 0.36787944117144233f;   // exp(-1/1)
    const float CO1 = 2.7182818284590452f;    // e/1
    const float R2  = 0.60653065971263342f;   // exp(-1/2)
    const float CO2 = 1.3591409142295226f;    // e/2
    const float CRF = -54.365636569180902f;   // -20e == -40e/2

    __syncthreads();

    for (int chk = 0; chk < 5; ++chk) {
        const int t0 = chk * TC;

        // ================= layer 1: conv1 + psp1 + spike1 =================
        if (cw) {
            float a[TC][4];
#pragma unroll
            for (int u = 0; u < TC; ++u) { a[u][0]=0.f; a[u][1]=0.f; a[u][2]=0.f; a[u][3]=0.f; }
            if (cin) {
#pragma unroll 1
                for (int ic = 0; ic < 4; ++ic) {
                    const uint2*  xp = &xm[ic][xbase];
                    const float4* wp = (const float4*)&wL1[ic * 100];
#pragma unroll 1
                    for (int dy = 0; dy < 5; ++dy) {
#pragma unroll
                        for (int dx = 0; dx < 5; ++dx) {
                            uint2 m = xp[dx];
                            unsigned long long mm =
                                ((unsigned long long)m.y << 32) | m.x;
                            unsigned win = (unsigned)(mm >> t0);
                            float4 w = wp[dx];
#pragma unroll
                            for (int u = 0; u < TC; ++u) {
                                float f = (float)((win >> u) & 1u);
                                a[u][0] = fmaf(f, w.x, a[u][0]);
                                a[u][1] = fmaf(f, w.y, a[u][1]);
                                a[u][2] = fmaf(f, w.z, a[u][2]);
                                a[u][3] = fmaf(f, w.w, a[u][3]);
                            }
                        }
                        xp += R1S; wp += 5;
                    }
                }
            }
            unsigned cm[4] = {0, 0, 0, 0};
#pragma unroll
            for (int u = 0; u < TC; ++u) {
#pragma unroll
                for (int oc = 0; oc < 4; ++oc) {
                    float ao  = CO1 * s2a[oc];
                    float ns1 = fmaf(R1, s1a[oc], a[u][oc]);
                    s1a[oc] = ns1;
                    s2a[oc] = fmaf(R1, s2a[oc], R1 * ns1);
                    float mv = fmaf(CRF, s2b[oc], ao);
                    unsigned b = (mv >= 20.f) ? 1u : 0u;
                    float spf = (float)b;
                    float nb1 = fmaf(R1, s1b[oc], spf);
                    s1b[oc] = nb1;
                    s2b[oc] = fmaf(R1, s2b[oc], R1 * nb1);
                    cm[oc] |= b << u;
                }
            }
            s1m[0][tid] = cm[0];
            s1m[1][tid] = cm[1];
            s1m[2][tid] = cm[2];
            s1m[3][tid] = cm[3];
        }
        __syncthreads();

        // ================= layer 2: conv2 + psp2 + spike2 =================
        if (tid < 256) {
            float a[TC][4];
#pragma unroll
            for (int u = 0; u < TC; ++u) { a[u][0]=0.f; a[u][1]=0.f; a[u][2]=0.f; a[u][3]=0.f; }
#pragma unroll 1
            for (int ic = 0; ic < 4; ++ic) {
                const unsigned* sp = &s1m[ic][ibase];
                const float4*   wp = (const float4*)&wL2[ic * 36];
#pragma unroll 1
                for (int dy = 0; dy < 3; ++dy) {
#pragma unroll
                    for (int dx = 0; dx < 3; ++dx) {
                        unsigned win = sp[dx];
                        float4 w = wp[dx];
#pragma unroll
                        for (int u = 0; u < TC; ++u) {
                            float f = (float)((win >> u) & 1u);
                            a[u][0] = fmaf(f, w.x, a[u][0]);
                            a[u][1] = fmaf(f, w.y, a[u][1]);
                            a[u][2] = fmaf(f, w.z, a[u][2]);
                            a[u][3] = fmaf(f, w.w, a[u][3]);
                        }
                    }
                    sp += R2S; wp += 3;
                }
            }
            unsigned cm[4] = {0, 0, 0, 0};
#pragma unroll
            for (int u = 0; u < TC; ++u) {
#pragma unroll
                for (int oc = 0; oc < 4; ++oc) {
                    float ao  = CO2 * s2c[oc];
                    float ns1 = fmaf(R2, s1c[oc], a[u][oc]);
                    s1c[oc] = ns1;
                    s2c[oc] = fmaf(R2, s2c[oc], R2 * ns1);
                    float mv = fmaf(CRF, s2d[oc], ao);
                    unsigned b = (mv >= 40.f) ? 1u : 0u;
                    float spf = (float)b;
                    float nd1 = fmaf(R2, s1d[oc], spf);
                    s1d[oc] = nd1;
                    s2d[oc] = fmaf(R2, s2d[oc], R2 * nd1);
                    cm[oc] |= b << u;
                }
            }
#pragma unroll
            for (int oc = 0; oc < 4; ++oc)
                om[oc] |= (unsigned long long)cm[oc] << t0;
        }
        __syncthreads();   // protect s1m reads vs next chunk's writes
    }

    // ---- epilogue: expand output bitmasks to floats ----
    if (tid < 256) {
#pragma unroll
        for (int c = 0; c < 4; ++c) {
            float* p = out + ((size_t)(((n * 4 + c) * 128 + (Y0 + iy)) * 128 + (X0 + ix))) * 50;
            unsigned long long m = om[c];
#pragma unroll
            for (int j = 0; j < 25; ++j) {
                int k = 2 * j;
                float2 v;
                v.x = (float)((unsigned)(m >> k) & 1u);
                v.y = (float)((unsigned)(m >> (k + 1)) & 1u);
                *(float2*)(p + k) = v;
            }
        }
    }
}

extern "C" void kernel_launch(void* const* d_in, const int* in_sizes, int n_in,
                              void* d_out, int out_size, void* d_ws, size_t ws_size,
                              hipStream_t stream) {
    (void)in_sizes; (void)n_in; (void)out_size; (void)d_ws; (void)ws_size;
    const float* x  = (const float*)d_in[0];
    const float* w1 = (const float*)d_in[1];
    const float* w2 = (const float*)d_in[2];
    float* o = (float*)d_out;
    dim3 grid(128 / TILE, 128 / TILE, 8);   // 512 blocks
    dim3 block(512);
    hipLaunchKernelGGL(snn_fused, grid, block, 0, stream, x, w1, w2, o);
}

// Round 5
// 412.719 us; speedup vs baseline: 1.0356x; 1.0356x over previous
//
#include <hip/hip_runtime.h>

// Fused SLAYER 2-layer SNN forward, time-chunked bitmask version.
// R5: 16x8 tiles, 1024 blocks x 256 threads -> 4 blocks/CU (was grid-limited
// to 2), targeting the occupancy bottleneck seen in R3 (Occ 19%, VALU 52%).
// R4's 512-thread attempt spilled (launch_bounds(512,4) => VGPR capped 64,
// WRITE_SIZE +52GB); this keeps 256-thread blocks and VGPR<=128.
//
// psp commutes with the per-timestep spatial conv -> conv BINARY spikes,
// apply psp after. Spikes live as bitmasks; convs amortize LDS mask/weight
// reads over TC=10 timesteps. Recurrence arithmetic identical to R3 (absmax 0).

#define TW   16                 // tile width
#define TH   8                  // tile height
#define R1S  (TW + 6)           // 22: x-mask region row stride/width
#define R1R  (TH + 6)           // 14: x-mask region rows
#define R1N  (R1S * R1R)        // 308
#define R2S  (TW + 2)           // 18: layer-1 spike region width
#define R2R  (TH + 2)           // 10: rows
#define R2N  (R2S * R2R)        // 180
#define TC   10                 // timesteps per chunk (50 = 5 chunks)

__global__ __launch_bounds__(256, 4)
void snn_fused(const float* __restrict__ xin,
               const float* __restrict__ w1,
               const float* __restrict__ w2,
               float* __restrict__ out)
{
    __shared__ __align__(16) uint2    xm[4][R1N];   // input spike masks (all 50 t)
    __shared__ unsigned               s1m[4][R2N];  // layer-1 spike masks (per chunk)
    __shared__ __align__(16) float    wL1[400];     // [ic][dy][dx][oc]
    __shared__ __align__(16) float    wL2[144];     // [ic][dy][dx][oc]

    const int tid = threadIdx.x;
    const int n   = blockIdx.z;
    const int Y0  = blockIdx.y * TH;
    const int X0  = blockIdx.x * TW;

    // ---- stage weights, transposed to [ic][dy][dx][oc] ----
    for (int i = tid; i < 400; i += 256) {
        int oc = i & 3, r = i >> 2;
        int ic = r / 25, r2 = r - ic * 25;
        int dy = r2 / 5, dx = r2 - dy * 5;
        wL1[i] = w1[((oc * 4 + ic) * 5 + dy) * 5 + dx];
    }
    if (tid < 144) {
        int oc = tid & 3, r = tid >> 2;
        int ic = r / 9, r2 = r - ic * 9;
        int dy = r2 / 3, dx = r2 - dy * 3;
        wL2[tid] = w2[((oc * 4 + ic) * 3 + dy) * 3 + dx];
    }

    // ---- pack input spikes (50 floats) into 64-bit masks, once ----
#pragma unroll
    for (int s = 0; s < 2; ++s) {
        int hp = tid + s * 256;
        if (hp < R1N) {
            int hy = hp / R1S, hx = hp - hy * R1S;
            int gy = Y0 + hy - 3, gx = X0 + hx - 3;
            bool inimg = gy >= 0 && gy < 128 && gx >= 0 && gx < 128;
#pragma unroll
            for (int c = 0; c < 4; ++c) {
                unsigned m0 = 0, m1 = 0;
                if (inimg) {
                    const float2* p = (const float2*)
                        (xin + ((size_t)(((n * 4 + c) * 128 + gy) * 128 + gx)) * 50);
#pragma unroll
                    for (int j = 0; j < 25; ++j) {
                        float2 v = p[j];
                        unsigned b0 = (v.x != 0.f) ? 1u : 0u;
                        unsigned b1 = (v.y != 0.f) ? 1u : 0u;
                        int k = 2 * j;
                        if (k < 32) m0 |= (b0 << k) | (b1 << (k + 1));
                        else        m1 |= (b0 << (k - 32)) | (b1 << (k - 31));
                    }
                }
                xm[c][hp] = make_uint2(m0, m1);
            }
        }
    }

    // ---- layer-1 region slot (10x18 = 180 px, single slot) ----
    const bool cw = (tid < R2N);
    const int cy = tid / R2S;
    const int cx = tid - cy * R2S;
    const bool cin = cw && (Y0 + cy - 1) >= 0 && (Y0 + cy - 1) < 128
                        && (X0 + cx - 1) >= 0 && (X0 + cx - 1) < 128;
    const int xbase = cy * R1S + cx;

    // ---- interior pixel (8x16 = 128 px, waves 0-1) ----
    const bool iw = (tid < TW * TH);
    const int iy = tid >> 4, ix = tid & 15;
    const int ibase = iy * R2S + ix;

    // persistent recurrence states
    float s1a[4] = {}, s2a[4] = {}, s1b[4] = {}, s2b[4] = {};
    float s1c[4] = {}, s2c[4] = {}, s1d[4] = {}, s2d[4] = {};
    unsigned long long om[4] = {};

    const float R1  = 0.36787944117144233f;   // exp(-1/1)
    const float CO1 = 2.7182818284590452f;    // e/1
    const float R2  = 0.60653065971263342f;   // exp(-1/2)
    const float CO2 = 1.3591409142295226f;    // e/2
    const float CRF = -54.365636569180902f;   // -20e == -40e/2

    __syncthreads();

    for (int chk = 0; chk < 5; ++chk) {
        const int t0 = chk * TC;

        // ================= layer 1: conv1 + psp1 + spike1 =================
        if (cw) {
            float a[TC][4];
#pragma unroll
            for (int u = 0; u < TC; ++u) { a[u][0]=0.f; a[u][1]=0.f; a[u][2]=0.f; a[u][3]=0.f; }
            if (cin) {
#pragma unroll 1
                for (int ic = 0; ic < 4; ++ic) {
                    const uint2*  xp = &xm[ic][xbase];
                    const float4* wp = (const float4*)&wL1[ic * 100];
#pragma unroll 1
                    for (int dy = 0; dy < 5; ++dy) {
#pragma unroll
                        for (int dx = 0; dx < 5; ++dx) {
                            uint2 m = xp[dx];
                            unsigned long long mm =
                                ((unsigned long long)m.y << 32) | m.x;
                            unsigned win = (unsigned)(mm >> t0);
                            float4 w = wp[dx];
#pragma unroll
                            for (int u = 0; u < TC; ++u) {
                                float f = (float)((win >> u) & 1u);
                                a[u][0] = fmaf(f, w.x, a[u][0]);
                                a[u][1] = fmaf(f, w.y, a[u][1]);
                                a[u][2] = fmaf(f, w.z, a[u][2]);
                                a[u][3] = fmaf(f, w.w, a[u][3]);
                            }
                        }
                        xp += R1S; wp += 5;
                    }
                }
            }
            unsigned cm[4] = {0, 0, 0, 0};
#pragma unroll
            for (int u = 0; u < TC; ++u) {
#pragma unroll
                for (int oc = 0; oc < 4; ++oc) {
                    float ao  = CO1 * s2a[oc];
                    float ns1 = fmaf(R1, s1a[oc], a[u][oc]);
                    s1a[oc] = ns1;
                    s2a[oc] = fmaf(R1, s2a[oc], R1 * ns1);
                    float mv = fmaf(CRF, s2b[oc], ao);
                    unsigned b = (mv >= 20.f) ? 1u : 0u;
                    float spf = (float)b;
                    float nb1 = fmaf(R1, s1b[oc], spf);
                    s1b[oc] = nb1;
                    s2b[oc] = fmaf(R1, s2b[oc], R1 * nb1);
                    cm[oc] |= b << u;
                }
            }
            s1m[0][tid] = cm[0];
            s1m[1][tid] = cm[1];
            s1m[2][tid] = cm[2];
            s1m[3][tid] = cm[3];
        }
        __syncthreads();

        // ================= layer 2: conv2 + psp2 + spike2 =================
        if (iw) {
            float a[TC][4];
#pragma unroll
            for (int u = 0; u < TC; ++u) { a[u][0]=0.f; a[u][1]=0.f; a[u][2]=0.f; a[u][3]=0.f; }
#pragma unroll 1
            for (int ic = 0; ic < 4; ++ic) {
                const unsigned* sp = &s1m[ic][ibase];
                const float4*   wp = (const float4*)&wL2[ic * 36];
#pragma unroll 1
                for (int dy = 0; dy < 3; ++dy) {
#pragma unroll
                    for (int dx = 0; dx < 3; ++dx) {
                        unsigned win = sp[dx];
                        float4 w = wp[dx];
#pragma unroll
                        for (int u = 0; u < TC; ++u) {
                            float f = (float)((win >> u) & 1u);
                            a[u][0] = fmaf(f, w.x, a[u][0]);
                            a[u][1] = fmaf(f, w.y, a[u][1]);
                            a[u][2] = fmaf(f, w.z, a[u][2]);
                            a[u][3] = fmaf(f, w.w, a[u][3]);
                        }
                    }
                    sp += R2S; wp += 3;
                }
            }
            unsigned cm[4] = {0, 0, 0, 0};
#pragma unroll
            for (int u = 0; u < TC; ++u) {
#pragma unroll
                for (int oc = 0; oc < 4; ++oc) {
                    float ao  = CO2 * s2c[oc];
                    float ns1 = fmaf(R2, s1c[oc], a[u][oc]);
                    s1c[oc] = ns1;
                    s2c[oc] = fmaf(R2, s2c[oc], R2 * ns1);
                    float mv = fmaf(CRF, s2d[oc], ao);
                    unsigned b = (mv >= 40.f) ? 1u : 0u;
                    float spf = (float)b;
                    float nd1 = fmaf(R2, s1d[oc], spf);
                    s1d[oc] = nd1;
                    s2d[oc] = fmaf(R2, s2d[oc], R2 * nd1);
                    cm[oc] |= b << u;
                }
            }
#pragma unroll
            for (int oc = 0; oc < 4; ++oc)
                om[oc] |= (unsigned long long)cm[oc] << t0;
        }
        __syncthreads();   // protect s1m reads vs next chunk's writes
    }

    // ---- epilogue: expand output bitmasks to floats ----
    if (iw) {
#pragma unroll
        for (int c = 0; c < 4; ++c) {
            float* p = out + ((size_t)(((n * 4 + c) * 128 + (Y0 + iy)) * 128 + (X0 + ix))) * 50;
            unsigned long long m = om[c];
#pragma unroll
            for (int j = 0; j < 25; ++j) {
                int k = 2 * j;
                float2 v;
                v.x = (float)((unsigned)(m >> k) & 1u);
                v.y = (float)((unsigned)(m >> (k + 1)) & 1u);
                *(float2*)(p + k) = v;
            }
        }
    }
}

extern "C" void kernel_launch(void* const* d_in, const int* in_sizes, int n_in,
                              void* d_out, int out_size, void* d_ws, size_t ws_size,
                              hipStream_t stream) {
    (void)in_sizes; (void)n_in; (void)out_size; (void)d_ws; (void)ws_size;
    const float* x  = (const float*)d_in[0];
    const float* w1 = (const float*)d_in[1];
    const float* w2 = (const float*)d_in[2];
    float* o = (float*)d_out;
    dim3 grid(128 / TW, 128 / TH, 8);   // 8 x 16 x 8 = 1024 blocks
    dim3 block(256);
    hipLaunchKernelGGL(snn_fused, grid, block, 0, stream, x, w1, w2, o);
}